// Round 3
// baseline (779.900 us; speedup 1.0000x reference)
//
#include <hip/hip_runtime.h>

// MoE top-2, E=8, T=8192, H=1024, I=2816. bf16 MFMA grouped-GEMM pipeline.
// R3: counted-vmcnt double-buffered K-loop (T3/T4), phase-split MFMA + setprio (T5),
//     raw s_barrier. Gateup BM128/BN64 dual-B; down BM128/BN128.

#define T_TOK 8192
#define H_DIM 1024
#define I_DIM 2816
#define NEXP  8
#define CAP   8192

typedef short bf16x8 __attribute__((ext_vector_type(8)));
typedef float f32x4  __attribute__((ext_vector_type(4)));

static __device__ __forceinline__ unsigned short f2bf(float f) {
  unsigned u = __float_as_uint(f);
  u = u + 0x7fffu + ((u >> 16) & 1u);   // RNE
  return (unsigned short)(u >> 16);
}

#define MFMA16x16x32(acc, a, b) \
  asm("v_mfma_f32_16x16x32_bf16 %0, %1, %2, %0" : "+v"(acc) : "v"(a), "v"(b))

#define GLD16(g, l) \
  __builtin_amdgcn_global_load_lds((const __attribute__((address_space(1))) void*)(g), \
                                   (__attribute__((address_space(3))) void*)(l), 16, 0, 0)

#define FENCE() asm volatile("" ::: "memory")

// ---------------- router ----------------
__global__ __launch_bounds__(256) void router_kernel(
    const float* __restrict__ x, const float* __restrict__ wr,
    int* __restrict__ cnt, int* __restrict__ tokL, float* __restrict__ wgtL,
    unsigned short* __restrict__ xb) {
  __shared__ float rw[NEXP * H_DIM];
  int tid = threadIdx.x;
#pragma unroll
  for (int it = 0; it < 8; ++it) {
    int i4 = it * 256 + tid;
    ((float4*)rw)[i4] = ((const float4*)wr)[i4];
  }
  __syncthreads();
  int wid = tid >> 6, lane = tid & 63;
  int t = blockIdx.x * 4 + wid;
  float a[NEXP];
#pragma unroll
  for (int e = 0; e < NEXP; ++e) a[e] = 0.f;
#pragma unroll
  for (int hc = 0; hc < H_DIM / 64; ++hc) {
    int h = hc * 64 + lane;
    float xv = x[(size_t)t * H_DIM + h];
    xb[(size_t)t * H_DIM + h] = f2bf(xv);
#pragma unroll
    for (int e = 0; e < NEXP; ++e) a[e] += xv * rw[e * H_DIM + h];
  }
#pragma unroll
  for (int e = 0; e < NEXP; ++e) {
    float v = a[e];
    for (int off = 32; off > 0; off >>= 1) v += __shfl_xor(v, off, 64);
    a[e] = v;
  }
  if (lane == 0) {
    int e1 = 0; float l1 = a[0];
#pragma unroll
    for (int e = 1; e < NEXP; ++e) if (a[e] > l1) { l1 = a[e]; e1 = e; }
    int e2 = -1; float l2 = -3.4e38f;
#pragma unroll
    for (int e = 0; e < NEXP; ++e) if (e != e1 && a[e] > l2) { l2 = a[e]; e2 = e; }
    float q = expf(l2 - l1);
    float w1 = 1.f / (1.f + q);
    float w2 = q * w1;
    int p1 = atomicAdd(&cnt[e1], 1);
    tokL[e1 * CAP + p1] = t; wgtL[e1 * CAP + p1] = w1;
    int p2 = atomicAdd(&cnt[e2], 1);
    tokL[e2 * CAP + p2] = t; wgtL[e2 * CAP + p2] = w2;
  }
}

__global__ void scan_kernel(const int* __restrict__ cnt, int* __restrict__ offs) {
  if (threadIdx.x == 0) {
    int s = 0;
    for (int e = 0; e < NEXP; ++e) { offs[e] = s; s += cnt[e]; }
  }
}

// ---------------- transpose + cast ----------------
__global__ __launch_bounds__(256) void transpose_kernel(
    const float* __restrict__ src, unsigned short* __restrict__ dst, int R, int C) {
  __shared__ float tile[64][65];
  int m = blockIdx.z;
  int r0 = blockIdx.y * 64, c0 = blockIdx.x * 64;
  const float* s = src + (size_t)m * R * C;
  unsigned short* d = dst + (size_t)m * R * C;
  int tid = threadIdx.x;
#pragma unroll
  for (int it = 0; it < 4; ++it) {
    int id4 = it * 256 + tid;
    int r = id4 >> 4, c4 = (id4 & 15) * 4;
    float4 v = *(const float4*)(s + (size_t)(r0 + r) * C + c0 + c4);
    tile[r][c4] = v.x; tile[r][c4 + 1] = v.y; tile[r][c4 + 2] = v.z; tile[r][c4 + 3] = v.w;
  }
  __syncthreads();
#pragma unroll
  for (int it = 0; it < 4; ++it) {
    int qd = it * 256 + tid;
    int c = qd >> 4, rq = (qd & 15) * 4;
    ushort4 o;
    o.x = f2bf(tile[rq][c]);     o.y = f2bf(tile[rq + 1][c]);
    o.z = f2bf(tile[rq + 2][c]); o.w = f2bf(tile[rq + 3][c]);
    *(ushort4*)(d + (size_t)(c0 + c) * R + r0 + rq) = o;
  }
}

// ---------------- gate+up fused grouped GEMM (pipelined) ----------------
// LDS linear tiles; physical (row,c16) holds logical (row, c16^(row&7)).
__global__ __launch_bounds__(256) void gateup_kernel(
    const unsigned short* __restrict__ xb,
    const unsigned short* __restrict__ wgT,   // [E][I][H] bf16
    const unsigned short* __restrict__ wuT,
    const int* __restrict__ cnt, const int* __restrict__ offs,
    const int* __restrict__ tokL,
    unsigned short* __restrict__ hbuf) {
  int e = blockIdx.z;
  int cnt_e = cnt[e];
  int m0 = blockIdx.y * 128;
  if (m0 >= cnt_e) return;
  int n0 = blockIdx.x * 64;
  int rcnt = cnt_e - m0; if (rcnt > 128) rcnt = 128;

  __shared__ unsigned short As[2][128 * 64], Gs[2][64 * 64], Us[2][64 * 64];  // 64 KB
  __shared__ int trow[128];
  int tid = threadIdx.x;
  if (tid < 128) trow[tid] = tokL[e * CAP + m0 + ((tid < rcnt) ? tid : 0)];
  __syncthreads();

  int lane = tid & 63, wid = tid >> 6;
  int lr = lane >> 3;
  int csrc = ((lane & 7) ^ lr) * 8;          // pre-swizzled source col (shorts)

  const unsigned short* pA[4]; const unsigned short* pG[2]; const unsigned short* pU[2];
  int oA[4], oGU[2];
#pragma unroll
  for (int i = 0; i < 4; ++i) {
    int row = (i * 4 + wid) * 8 + lr;
    pA[i] = xb + (size_t)trow[row] * H_DIM + csrc;
    oA[i] = (i * 4 + wid) * 512;
  }
#pragma unroll
  for (int i = 0; i < 2; ++i) {
    int row = (i * 4 + wid) * 8 + lr;
    size_t wrow = ((size_t)e * I_DIM + n0 + row) * H_DIM + csrc;
    pG[i] = wgT + wrow; pU[i] = wuT + wrow;
    oGU[i] = (i * 4 + wid) * 512;
  }

#define STAGE_GU(b, kt) do { int k0_ = (kt) * 64;                                   \
    _Pragma("unroll") for (int i_ = 0; i_ < 4; ++i_) GLD16(pA[i_] + k0_, &As[b][oA[i_]]); \
    _Pragma("unroll") for (int i_ = 0; i_ < 2; ++i_) {                              \
      GLD16(pG[i_] + k0_, &Gs[b][oGU[i_]]);                                         \
      GLD16(pU[i_] + k0_, &Us[b][oGU[i_]]); } } while (0)

  int wr = wid >> 1, wc = wid & 1;
  int fr = lane & 15, fg = lane >> 4;
  int fsw = fr & 7;

  f32x4 accg[4][2], accu[4][2];
#pragma unroll
  for (int m = 0; m < 4; ++m)
#pragma unroll
    for (int n = 0; n < 2; ++n) { accg[m][n] = (f32x4)0.f; accu[m][n] = (f32x4)0.f; }

  STAGE_GU(0, 0);

  for (int kt = 0; kt < H_DIM / 64; ++kt) {   // 16 K-tiles
    int cur = kt & 1;
    __builtin_amdgcn_s_barrier();             // all waves done reading buf[cur^1]
    FENCE();
    if (kt + 1 < H_DIM / 64) {
      STAGE_GU(cur ^ 1, kt + 1);
      asm volatile("s_waitcnt vmcnt(12)" ::: "memory");   // kt's 12 loads landed
    } else {
      asm volatile("s_waitcnt vmcnt(0)" ::: "memory");
    }
    __builtin_amdgcn_s_barrier();             // collective: kt ready
    FENCE();
    const unsigned short* Ab = &As[cur][0];
    const unsigned short* Gb = &Gs[cur][0];
    const unsigned short* Ub = &Us[cur][0];
    int cb0 = ((0 * 4 + fg) ^ fsw) * 8;
    int cb1 = ((1 * 4 + fg) ^ fsw) * 8;
    bf16x8 bg[2][2], bu[2][2];
#pragma unroll
    for (int n = 0; n < 2; ++n) {
      bg[n][0] = *(const bf16x8*)(Gb + (wc * 32 + n * 16 + fr) * 64 + cb0);
      bg[n][1] = *(const bf16x8*)(Gb + (wc * 32 + n * 16 + fr) * 64 + cb1);
      bu[n][0] = *(const bf16x8*)(Ub + (wc * 32 + n * 16 + fr) * 64 + cb0);
      bu[n][1] = *(const bf16x8*)(Ub + (wc * 32 + n * 16 + fr) * 64 + cb1);
    }
#pragma unroll
    for (int mq = 0; mq < 4; ++mq) {
      bf16x8 am0 = *(const bf16x8*)(Ab + (wr * 64 + mq * 16 + fr) * 64 + cb0);
      bf16x8 am1 = *(const bf16x8*)(Ab + (wr * 64 + mq * 16 + fr) * 64 + cb1);
      __builtin_amdgcn_s_setprio(1);
      MFMA16x16x32(accg[mq][0], am0, bg[0][0]); MFMA16x16x32(accg[mq][0], am1, bg[0][1]);
      MFMA16x16x32(accg[mq][1], am0, bg[1][0]); MFMA16x16x32(accg[mq][1], am1, bg[1][1]);
      MFMA16x16x32(accu[mq][0], am0, bu[0][0]); MFMA16x16x32(accu[mq][0], am1, bu[0][1]);
      MFMA16x16x32(accu[mq][1], am0, bu[1][0]); MFMA16x16x32(accu[mq][1], am1, bu[1][1]);
      __builtin_amdgcn_s_setprio(0);
    }
  }
#undef STAGE_GU

  int hb = offs[e];
#pragma unroll
  for (int mq = 0; mq < 4; ++mq)
#pragma unroll
    for (int q = 0; q < 4; ++q) {
      int row = wr * 64 + mq * 16 + fg * 4 + q;
      if (row < rcnt) {
        size_t rbase = (size_t)(hb + m0 + row) * I_DIM + n0 + wc * 32;
#pragma unroll
        for (int n = 0; n < 2; ++n) {
          float g = accg[mq][n][q], u = accu[mq][n][q];
          hbuf[rbase + n * 16 + fr] = f2bf(g / (1.f + expf(-g)) * u);
        }
      }
    }
}

// ---------------- down grouped GEMM (pipelined) + weighted scatter-add ----------------
__global__ __launch_bounds__(256) void down_kernel(
    const unsigned short* __restrict__ hbuf,
    const unsigned short* __restrict__ wdT,   // [E][H][I] bf16
    const int* __restrict__ cnt, const int* __restrict__ offs,
    const int* __restrict__ tokL, const float* __restrict__ wgtL,
    float* __restrict__ out) {
  int e = blockIdx.z;
  int cnt_e = cnt[e];
  int m0 = blockIdx.y * 128;
  if (m0 >= cnt_e) return;
  int n0 = blockIdx.x * 128;
  int rcnt = cnt_e - m0; if (rcnt > 128) rcnt = 128;
  int hb = offs[e];

  __shared__ unsigned short As[2][128 * 64], Bs[2][128 * 64];   // 64 KB
  int tid = threadIdx.x, lane = tid & 63, wid = tid >> 6;
  int lr = lane >> 3;
  int csrc = ((lane & 7) ^ lr) * 8;

  const unsigned short* pA[4]; const unsigned short* pB[4];
  int oAB[4];
#pragma unroll
  for (int i = 0; i < 4; ++i) {
    int row = (i * 4 + wid) * 8 + lr;
    int rowc = (row < rcnt) ? row : (rcnt - 1);
    pA[i] = hbuf + (size_t)(hb + m0 + rowc) * I_DIM + csrc;
    pB[i] = wdT + ((size_t)e * H_DIM + n0 + row) * I_DIM + csrc;
    oAB[i] = (i * 4 + wid) * 512;
  }

#define STAGE_D(b, kt) do { int k0_ = (kt) * 64;                                    \
    _Pragma("unroll") for (int i_ = 0; i_ < 4; ++i_) {                              \
      GLD16(pA[i_] + k0_, &As[b][oAB[i_]]);                                         \
      GLD16(pB[i_] + k0_, &Bs[b][oAB[i_]]); } } while (0)

  int wr = wid >> 1, wc = wid & 1, fr = lane & 15, fg = lane >> 4;
  int fsw = fr & 7;

  f32x4 acc[4][4];
#pragma unroll
  for (int m = 0; m < 4; ++m)
#pragma unroll
    for (int n = 0; n < 4; ++n) acc[m][n] = (f32x4)0.f;

  STAGE_D(0, 0);

  for (int kt = 0; kt < I_DIM / 64; ++kt) {   // 44 K-tiles
    int cur = kt & 1;
    __builtin_amdgcn_s_barrier();
    FENCE();
    if (kt + 1 < I_DIM / 64) {
      STAGE_D(cur ^ 1, kt + 1);
      asm volatile("s_waitcnt vmcnt(8)" ::: "memory");
    } else {
      asm volatile("s_waitcnt vmcnt(0)" ::: "memory");
    }
    __builtin_amdgcn_s_barrier();
    FENCE();
    const unsigned short* Ab = &As[cur][0];
    const unsigned short* Bb = &Bs[cur][0];
    int cb0 = ((0 * 4 + fg) ^ fsw) * 8;
    int cb1 = ((1 * 4 + fg) ^ fsw) * 8;
    bf16x8 bn[4][2];
#pragma unroll
    for (int n = 0; n < 4; ++n) {
      bn[n][0] = *(const bf16x8*)(Bb + (wc * 64 + n * 16 + fr) * 64 + cb0);
      bn[n][1] = *(const bf16x8*)(Bb + (wc * 64 + n * 16 + fr) * 64 + cb1);
    }
#pragma unroll
    for (int mq = 0; mq < 4; ++mq) {
      bf16x8 am0 = *(const bf16x8*)(Ab + (wr * 64 + mq * 16 + fr) * 64 + cb0);
      bf16x8 am1 = *(const bf16x8*)(Ab + (wr * 64 + mq * 16 + fr) * 64 + cb1);
      __builtin_amdgcn_s_setprio(1);
#pragma unroll
      for (int n = 0; n < 4; ++n) {
        MFMA16x16x32(acc[mq][n], am0, bn[n][0]);
        MFMA16x16x32(acc[mq][n], am1, bn[n][1]);
      }
      __builtin_amdgcn_s_setprio(0);
    }
  }
#undef STAGE_D

#pragma unroll
  for (int mq = 0; mq < 4; ++mq)
#pragma unroll
    for (int q = 0; q < 4; ++q) {
      int row = wr * 64 + mq * 16 + fg * 4 + q;
      if (row < rcnt) {
        float w = wgtL[e * CAP + m0 + row];
        int t = tokL[e * CAP + m0 + row];
        float* obase = out + (size_t)t * H_DIM + n0 + wc * 64;
#pragma unroll
        for (int n = 0; n < 4; ++n)
          atomicAdd(obase + n * 16 + fr, w * acc[mq][n][q]);
      }
    }
}

extern "C" void kernel_launch(void* const* d_in, const int* in_sizes, int n_in,
                              void* d_out, int out_size, void* d_ws, size_t ws_size,
                              hipStream_t stream) {
  const float* x   = (const float*)d_in[0];
  const float* wr  = (const float*)d_in[1];
  const float* wg  = (const float*)d_in[2];
  const float* wu  = (const float*)d_in[3];
  const float* wd  = (const float*)d_in[4];
  float* out = (float*)d_out;

  char* ws = (char*)d_ws;
  int*   cnt  = (int*)ws;
  int*   offs = (int*)(ws + 64);
  int*   tokL = (int*)(ws + 1024);
  float* wgtL = (float*)(ws + 1024 + (size_t)NEXP * CAP * 4);
  unsigned short* xb  = (unsigned short*)(ws + (1u << 20));
  unsigned short* wgT = (unsigned short*)(ws + (1u << 20) + (size_t)T_TOK * H_DIM * 2);
  unsigned short* wuT = wgT + (size_t)NEXP * I_DIM * H_DIM;
  unsigned short* wdT = wuT + (size_t)NEXP * I_DIM * H_DIM;
  unsigned short* hbuf = wdT + (size_t)NEXP * H_DIM * I_DIM;

  hipMemsetAsync(ws, 0, 64, stream);
  hipMemsetAsync(d_out, 0, (size_t)out_size * 4, stream);

  router_kernel<<<T_TOK / 4, 256, 0, stream>>>(x, wr, cnt, tokL, wgtL, xb);
  scan_kernel<<<1, 64, 0, stream>>>(cnt, offs);

  transpose_kernel<<<dim3(I_DIM / 64, H_DIM / 64, NEXP), 256, 0, stream>>>(wg, wgT, H_DIM, I_DIM);
  transpose_kernel<<<dim3(I_DIM / 64, H_DIM / 64, NEXP), 256, 0, stream>>>(wu, wuT, H_DIM, I_DIM);
  transpose_kernel<<<dim3(H_DIM / 64, I_DIM / 64, NEXP), 256, 0, stream>>>(wd, wdT, I_DIM, H_DIM);

  gateup_kernel<<<dim3(I_DIM / 64, CAP / 128, NEXP), 256, 0, stream>>>(
      xb, wgT, wuT, cnt, offs, tokL, hbuf);
  down_kernel<<<dim3(H_DIM / 128, CAP / 128, NEXP), 256, 0, stream>>>(
      hbuf, wdT, cnt, offs, tokL, wgtL, out);
}

// Round 4
// 737.397 us; speedup vs baseline: 1.0576x; 1.0576x over previous
//
#include <hip/hip_runtime.h>

// MoE top-2, E=8, T=8192, H=1024, I=2816. bf16 MFMA grouped-GEMM pipeline.
// R4: revert to R2 sync (stage -> sync -> compute -> sync). 512-thr blocks, BM=256,
//     16 waves/CU, XCD expert-chunk swizzle (T1), vectorized router.

#define T_TOK 8192
#define H_DIM 1024
#define I_DIM 2816
#define NEXP  8
#define CAP   8192

typedef short bf16x8 __attribute__((ext_vector_type(8)));
typedef float f32x4  __attribute__((ext_vector_type(4)));

static __device__ __forceinline__ unsigned short f2bf(float f) {
  unsigned u = __float_as_uint(f);
  u = u + 0x7fffu + ((u >> 16) & 1u);   // RNE
  return (unsigned short)(u >> 16);
}

#define MFMA16x16x32(acc, a, b) \
  asm("v_mfma_f32_16x16x32_bf16 %0, %1, %2, %0" : "+v"(acc) : "v"(a), "v"(b))

#define GLD16(g, l) \
  __builtin_amdgcn_global_load_lds((const __attribute__((address_space(1))) void*)(g), \
                                   (__attribute__((address_space(3))) void*)(l), 16, 0, 0)

// ---------------- router: logits, top-2 softmax, expert lists, x->bf16 ----------------
__global__ __launch_bounds__(256) void router_kernel(
    const float* __restrict__ x, const float* __restrict__ wr,
    int* __restrict__ cnt, int* __restrict__ tokL, float* __restrict__ wgtL,
    unsigned short* __restrict__ xb) {
  __shared__ float rw[NEXP * H_DIM];    // 32 KB
  int tid = threadIdx.x;
#pragma unroll
  for (int it = 0; it < 8; ++it) {
    int i4 = it * 256 + tid;
    ((float4*)rw)[i4] = ((const float4*)wr)[i4];
  }
  __syncthreads();
  int wid = tid >> 6, lane = tid & 63;
  int t = blockIdx.x * 4 + wid;         // one wave per token
  float a[NEXP];
#pragma unroll
  for (int e = 0; e < NEXP; ++e) a[e] = 0.f;
#pragma unroll
  for (int hc = 0; hc < 4; ++hc) {
    int h = hc * 256 + lane * 4;
    float4 xv = *(const float4*)(x + (size_t)t * H_DIM + h);
    ushort4 o;
    o.x = f2bf(xv.x); o.y = f2bf(xv.y); o.z = f2bf(xv.z); o.w = f2bf(xv.w);
    *(ushort4*)(xb + (size_t)t * H_DIM + h) = o;
#pragma unroll
    for (int e = 0; e < NEXP; ++e) {
      float4 w4 = *(const float4*)(&rw[e * H_DIM + h]);
      a[e] += xv.x * w4.x + xv.y * w4.y + xv.z * w4.z + xv.w * w4.w;
    }
  }
#pragma unroll
  for (int e = 0; e < NEXP; ++e) {
    float v = a[e];
    for (int off = 32; off > 0; off >>= 1) v += __shfl_xor(v, off, 64);
    a[e] = v;
  }
  if (lane == 0) {
    int e1 = 0; float l1 = a[0];
#pragma unroll
    for (int e = 1; e < NEXP; ++e) if (a[e] > l1) { l1 = a[e]; e1 = e; }
    int e2 = -1; float l2 = -3.4e38f;
#pragma unroll
    for (int e = 0; e < NEXP; ++e) if (e != e1 && a[e] > l2) { l2 = a[e]; e2 = e; }
    float q = expf(l2 - l1);
    float w1 = 1.f / (1.f + q);
    float w2 = q * w1;
    int p1 = atomicAdd(&cnt[e1], 1);
    tokL[e1 * CAP + p1] = t; wgtL[e1 * CAP + p1] = w1;
    int p2 = atomicAdd(&cnt[e2], 1);
    tokL[e2 * CAP + p2] = t; wgtL[e2 * CAP + p2] = w2;
  }
}

__global__ void scan_kernel(const int* __restrict__ cnt, int* __restrict__ offs) {
  if (threadIdx.x == 0) {
    int s = 0;
    for (int e = 0; e < NEXP; ++e) { offs[e] = s; s += cnt[e]; }
  }
}

// ---------------- transpose last-2-dims + f32->bf16: src [M][R][C] -> dst [M][C][R] ----------------
__global__ __launch_bounds__(256) void transpose_kernel(
    const float* __restrict__ src, unsigned short* __restrict__ dst, int R, int C) {
  __shared__ float tile[64][65];
  int m = blockIdx.z;
  int r0 = blockIdx.y * 64, c0 = blockIdx.x * 64;
  const float* s = src + (size_t)m * R * C;
  unsigned short* d = dst + (size_t)m * R * C;
  int tid = threadIdx.x;
#pragma unroll
  for (int it = 0; it < 4; ++it) {
    int id4 = it * 256 + tid;
    int r = id4 >> 4, c4 = (id4 & 15) * 4;
    float4 v = *(const float4*)(s + (size_t)(r0 + r) * C + c0 + c4);
    tile[r][c4] = v.x; tile[r][c4 + 1] = v.y; tile[r][c4 + 2] = v.z; tile[r][c4 + 3] = v.w;
  }
  __syncthreads();
#pragma unroll
  for (int it = 0; it < 4; ++it) {
    int qd = it * 256 + tid;
    int c = qd >> 4, rq = (qd & 15) * 4;
    ushort4 o;
    o.x = f2bf(tile[rq][c]);     o.y = f2bf(tile[rq + 1][c]);
    o.z = f2bf(tile[rq + 2][c]); o.w = f2bf(tile[rq + 3][c]);
    *(ushort4*)(d + (size_t)(c0 + c) * R + r0 + rq) = o;
  }
}

// ---------------- gate+up fused grouped GEMM + silu*mul -> h (bf16) ----------------
// BM=256, BN=64 (G and U each). 512 threads = 8 waves (4M x 2N). LDS ~49 KB.
// LDS linear; physical (row,c16) holds logical (row, c16^(row&7)).
__global__ __launch_bounds__(512, 4) void gateup_kernel(
    const unsigned short* __restrict__ xb,
    const unsigned short* __restrict__ wgT,   // [E][I][H] bf16
    const unsigned short* __restrict__ wuT,
    const int* __restrict__ cnt, const int* __restrict__ offs,
    const int* __restrict__ tokL,
    unsigned short* __restrict__ hbuf) {
  // 1-D grid 11264 = 8e * 44n * 32m; XCD chunk = one expert; m fastest within n.
  int flat = blockIdx.x;
  int wg = (flat & 7) * (11264 >> 3) + (flat >> 3);
  int e = wg / 1408;
  int r = wg % 1408;
  int n0 = (r >> 5) * 64;
  int m0 = (r & 31) * 256;
  int cnt_e = cnt[e];
  if (m0 >= cnt_e) return;
  int rcnt = cnt_e - m0; if (rcnt > 256) rcnt = 256;

  __shared__ unsigned short As[256 * 64];   // 32 KB
  __shared__ unsigned short Gs[64 * 64];    // 8 KB
  __shared__ unsigned short Us[64 * 64];    // 8 KB
  __shared__ int trow[256];
  int tid = threadIdx.x;
  if (tid < 256) trow[tid] = tokL[e * CAP + m0 + ((tid < rcnt) ? tid : 0)];
  __syncthreads();

  int lane = tid & 63, wid = tid >> 6;      // wid 0..7
  int lr = lane >> 3;
  int csrc = ((lane & 7) ^ lr) * 8;         // pre-swizzled source col (shorts)

  const unsigned short* pA[4];
  const unsigned short* pG;
  const unsigned short* pU;
  int oA[4], oGU;
#pragma unroll
  for (int i = 0; i < 4; ++i) {
    int chunk = i * 8 + wid;
    int row = chunk * 8 + lr;
    pA[i] = xb + (size_t)trow[row] * H_DIM + csrc;
    oA[i] = chunk * 512;
  }
  {
    int row = wid * 8 + lr;
    size_t wrow = ((size_t)e * I_DIM + n0 + row) * H_DIM + csrc;
    pG = wgT + wrow; pU = wuT + wrow;
    oGU = wid * 512;
  }

  int wr = wid >> 1, wc = wid & 1;
  int fr = lane & 15, fg = lane >> 4;
  int fsw = fr & 7;

  f32x4 accg[4][2], accu[4][2];
#pragma unroll
  for (int m = 0; m < 4; ++m)
#pragma unroll
    for (int n = 0; n < 2; ++n) { accg[m][n] = (f32x4)0.f; accu[m][n] = (f32x4)0.f; }

  for (int ks = 0; ks < H_DIM / 64; ++ks) {   // 16 K-steps
    int k0 = ks * 64;
#pragma unroll
    for (int i = 0; i < 4; ++i) GLD16(pA[i] + k0, As + oA[i]);
    GLD16(pG + k0, Gs + oGU);
    GLD16(pU + k0, Us + oGU);
    __syncthreads();
#pragma unroll
    for (int kk = 0; kk < 2; ++kk) {
      int cb = ((kk * 4 + fg) ^ fsw) * 8;
      bf16x8 bg[2], bu[2];
#pragma unroll
      for (int n = 0; n < 2; ++n) {
        bg[n] = *(const bf16x8*)(Gs + (wc * 32 + n * 16 + fr) * 64 + cb);
        bu[n] = *(const bf16x8*)(Us + (wc * 32 + n * 16 + fr) * 64 + cb);
      }
#pragma unroll
      for (int mq = 0; mq < 4; ++mq) {
        bf16x8 am = *(const bf16x8*)(As + (wr * 64 + mq * 16 + fr) * 64 + cb);
        MFMA16x16x32(accg[mq][0], am, bg[0]);
        MFMA16x16x32(accg[mq][1], am, bg[1]);
        MFMA16x16x32(accu[mq][0], am, bu[0]);
        MFMA16x16x32(accu[mq][1], am, bu[1]);
      }
    }
    __syncthreads();
  }

  int hb = offs[e];
#pragma unroll
  for (int mq = 0; mq < 4; ++mq)
#pragma unroll
    for (int q = 0; q < 4; ++q) {
      int row = wr * 64 + mq * 16 + fg * 4 + q;
      if (row < rcnt) {
        size_t rbase = (size_t)(hb + m0 + row) * I_DIM + n0 + wc * 32;
#pragma unroll
        for (int n = 0; n < 2; ++n) {
          float g = accg[mq][n][q], u = accu[mq][n][q];
          hbuf[rbase + n * 16 + fr] = f2bf(g / (1.f + expf(-g)) * u);
        }
      }
    }
}

// ---------------- down grouped GEMM + weighted scatter-add ----------------
// BM=256, BN=128. 512 threads = 8 waves (2M x 4N). LDS 48 KB.
__global__ __launch_bounds__(512, 4) void down_kernel(
    const unsigned short* __restrict__ hbuf,
    const unsigned short* __restrict__ wdT,   // [E][H][I] bf16
    const int* __restrict__ cnt, const int* __restrict__ offs,
    const int* __restrict__ tokL, const float* __restrict__ wgtL,
    float* __restrict__ out) {
  // 1-D grid 2048 = 8e * 8n * 32m; XCD chunk = one expert; m fastest.
  int flat = blockIdx.x;
  int wg = (flat & 7) * (2048 >> 3) + (flat >> 3);
  int e = wg / 256;
  int r = wg % 256;
  int n0 = (r >> 5) * 128;
  int m0 = (r & 31) * 256;
  int cnt_e = cnt[e];
  if (m0 >= cnt_e) return;
  int rcnt = cnt_e - m0; if (rcnt > 256) rcnt = 256;
  int hb = offs[e];

  __shared__ unsigned short As[256 * 64];   // 32 KB
  __shared__ unsigned short Bs[128 * 64];   // 16 KB
  int tid = threadIdx.x, lane = tid & 63, wid = tid >> 6;
  int lr = lane >> 3;
  int csrc = ((lane & 7) ^ lr) * 8;

  const unsigned short* pA[4];
  const unsigned short* pB[2];
  int oA[4], oB[2];
#pragma unroll
  for (int i = 0; i < 4; ++i) {
    int chunk = i * 8 + wid;
    int row = chunk * 8 + lr;
    int rowc = (row < rcnt) ? row : (rcnt - 1);
    pA[i] = hbuf + (size_t)(hb + m0 + rowc) * I_DIM + csrc;
    oA[i] = chunk * 512;
  }
#pragma unroll
  for (int i = 0; i < 2; ++i) {
    int chunk = i * 8 + wid;
    int row = chunk * 8 + lr;
    pB[i] = wdT + ((size_t)e * H_DIM + n0 + row) * I_DIM + csrc;
    oB[i] = chunk * 512;
  }

  int wr = wid & 1, wc = wid >> 1;          // 2M x 4N
  int fr = lane & 15, fg = lane >> 4;
  int fsw = fr & 7;

  f32x4 acc[8][2];
#pragma unroll
  for (int m = 0; m < 8; ++m)
#pragma unroll
    for (int n = 0; n < 2; ++n) acc[m][n] = (f32x4)0.f;

  for (int ks = 0; ks < I_DIM / 64; ++ks) {   // 44 K-steps
    int k0 = ks * 64;
#pragma unroll
    for (int i = 0; i < 4; ++i) GLD16(pA[i] + k0, As + oA[i]);
#pragma unroll
    for (int i = 0; i < 2; ++i) GLD16(pB[i] + k0, Bs + oB[i]);
    __syncthreads();
#pragma unroll
    for (int kk = 0; kk < 2; ++kk) {
      int cb = ((kk * 4 + fg) ^ fsw) * 8;
      bf16x8 bn[2];
#pragma unroll
      for (int n = 0; n < 2; ++n)
        bn[n] = *(const bf16x8*)(Bs + (wc * 32 + n * 16 + fr) * 64 + cb);
#pragma unroll
      for (int mq = 0; mq < 8; ++mq) {
        bf16x8 am = *(const bf16x8*)(As + (wr * 128 + mq * 16 + fr) * 64 + cb);
        MFMA16x16x32(acc[mq][0], am, bn[0]);
        MFMA16x16x32(acc[mq][1], am, bn[1]);
      }
    }
    __syncthreads();
  }

#pragma unroll
  for (int mq = 0; mq < 8; ++mq)
#pragma unroll
    for (int q = 0; q < 4; ++q) {
      int row = wr * 128 + mq * 16 + fg * 4 + q;
      if (row < rcnt) {
        float w = wgtL[e * CAP + m0 + row];
        int t = tokL[e * CAP + m0 + row];
        float* obase = out + (size_t)t * H_DIM + n0 + wc * 32;
#pragma unroll
        for (int n = 0; n < 2; ++n)
          atomicAdd(obase + n * 16 + fr, w * acc[mq][n][q]);
      }
    }
}

extern "C" void kernel_launch(void* const* d_in, const int* in_sizes, int n_in,
                              void* d_out, int out_size, void* d_ws, size_t ws_size,
                              hipStream_t stream) {
  const float* x   = (const float*)d_in[0];
  const float* wr  = (const float*)d_in[1];
  const float* wg  = (const float*)d_in[2];
  const float* wu  = (const float*)d_in[3];
  const float* wd  = (const float*)d_in[4];
  float* out = (float*)d_out;

  char* ws = (char*)d_ws;
  int*   cnt  = (int*)ws;
  int*   offs = (int*)(ws + 64);
  int*   tokL = (int*)(ws + 1024);
  float* wgtL = (float*)(ws + 1024 + (size_t)NEXP * CAP * 4);
  unsigned short* xb  = (unsigned short*)(ws + (1u << 20));
  unsigned short* wgT = (unsigned short*)(ws + (1u << 20) + (size_t)T_TOK * H_DIM * 2);
  unsigned short* wuT = wgT + (size_t)NEXP * I_DIM * H_DIM;
  unsigned short* wdT = wuT + (size_t)NEXP * I_DIM * H_DIM;
  unsigned short* hbuf = wdT + (size_t)NEXP * H_DIM * I_DIM;

  hipMemsetAsync(ws, 0, 64, stream);
  hipMemsetAsync(d_out, 0, (size_t)out_size * 4, stream);

  router_kernel<<<T_TOK / 4, 256, 0, stream>>>(x, wr, cnt, tokL, wgtL, xb);
  scan_kernel<<<1, 64, 0, stream>>>(cnt, offs);

  transpose_kernel<<<dim3(I_DIM / 64, H_DIM / 64, NEXP), 256, 0, stream>>>(wg, wgT, H_DIM, I_DIM);
  transpose_kernel<<<dim3(I_DIM / 64, H_DIM / 64, NEXP), 256, 0, stream>>>(wu, wuT, H_DIM, I_DIM);
  transpose_kernel<<<dim3(H_DIM / 64, I_DIM / 64, NEXP), 256, 0, stream>>>(wd, wdT, I_DIM, H_DIM);

  gateup_kernel<<<11264, 512, 0, stream>>>(xb, wgT, wuT, cnt, offs, tokL, hbuf);
  down_kernel<<<2048, 512, 0, stream>>>(hbuf, wdT, cnt, offs, tokL, wgtL, out);
}